// Round 14
// baseline (238.080 us; speedup 1.0000x reference)
//
#include <hip/hip_runtime.h>
#include <stdint.h>
#include <stddef.h>

// Problem constants
#define BB 2
#define TT 4096
#define EE 768
#define HH 12
#define DH 64
#define WW 256
#define NCHUNK 16
#define GG 16

typedef __bf16 bf16_t;
typedef __bf16 bf16x8 __attribute__((ext_vector_type(8)));
typedef float f32x4 __attribute__((ext_vector_type(4)));

__device__ inline f32x4 mfma16(bf16x8 a, bf16x8 b, f32x4 c) {
    return __builtin_amdgcn_mfma_f32_16x16x32_bf16(a, b, c, 0, 0, 0);
}

__device__ inline void gload16(const void* g, void* l) {
    __builtin_amdgcn_global_load_lds(
        (const __attribute__((address_space(1))) void*)g,
        (__attribute__((address_space(3))) void*)l, 16, 0, 0);
}

// ---------------- fused prep: blocks [0,3072) x->xb bf16; [3072,3792) W->Wt ----------
__global__ __launch_bounds__(256) void k_prep(const float* __restrict__ x,
                                              bf16_t* __restrict__ xb,
                                              const float* __restrict__ w0,
                                              const float* __restrict__ w1,
                                              const float* __restrict__ w2,
                                              const float* __restrict__ w3,
                                              const float* __restrict__ w4,
                                              bf16_t* __restrict__ wt) {
    __shared__ __align__(16) bf16_t ls[64 * 65];
    const int tid = threadIdx.x;
    if (blockIdx.x < 3072) {
        const int i = (blockIdx.x * 256 + tid) * 8;
        f32x4 a = *(const f32x4*)(x + i);
        f32x4 b = *(const f32x4*)(x + i + 4);
        bf16x8 o;
        o[0] = (bf16_t)a[0]; o[1] = (bf16_t)a[1]; o[2] = (bf16_t)a[2]; o[3] = (bf16_t)a[3];
        o[4] = (bf16_t)b[0]; o[5] = (bf16_t)b[1]; o[6] = (bf16_t)b[2]; o[7] = (bf16_t)b[3];
        *(bf16x8*)(xb + i) = o;
    } else {
        const int idx0 = blockIdx.x - 3072;         // 0..719
        const int z = idx0 / 144;
        const int rr = idx0 % 144;
        const int k0 = (rr / 12) * 64;
        const int n0 = (rr % 12) * 64;
        const float* W = (z == 0) ? w0 : (z == 1) ? w1 : (z == 2) ? w2 : (z == 3) ? w3 : w4;
        #pragma unroll
        for (int i = 0; i < 16; ++i) {
            int idx = i * 256 + tid;
            int kr = idx >> 6, nc = idx & 63;
            ls[nc * 65 + kr] = (bf16_t)W[(size_t)(k0 + kr) * EE + n0 + nc];
        }
        __syncthreads();
        bf16_t* o = wt + (size_t)z * EE * EE;
        #pragma unroll
        for (int i = 0; i < 16; ++i) {
            int idx = i * 256 + tid;
            int nr = idx >> 6, kc = idx & 63;
            o[(size_t)(n0 + nr) * EE + k0 + kc] = ls[nr * 65 + kc];
        }
    }
}

// ---------------- projection GEMM (v12, unchanged): dbuf, 1 barrier/K-step --------
__global__ __launch_bounds__(256) void k_gemm(const bf16_t* __restrict__ xb,
                                              const bf16_t* __restrict__ wt,
                                              const float* __restrict__ b0,
                                              const float* __restrict__ b1,
                                              const float* __restrict__ b2,
                                              const float* __restrict__ b3,
                                              const float* __restrict__ b4,
                                              bf16_t* __restrict__ proj,
                                              bf16_t* __restrict__ vTp) {
    const int tid = threadIdx.x;
    const int z = blockIdx.z;
    const int m0 = blockIdx.x * 128;
    const int n0 = blockIdx.y * 128;
    const float* bias = (z == 0) ? b0 : (z == 1) ? b1 : (z == 2) ? b2 : (z == 3) ? b3 : b4;
    const float scale = (z == 0) ? 0.125f : 1.0f;
    const bf16_t* wz = wt + (size_t)z * EE * EE;
    bf16_t* dst = proj + (size_t)z * BB * HH * TT * DH;

    __shared__ __align__(16) char smem[65536];
    bf16_t* ct = (bf16_t*)smem;             // [128*128] overlay

    const int lane = tid & 63, wid = tid >> 6;
    const int wr = wid >> 1, wc = wid & 1;
    const int lg = lane >> 4, lr = lane & 15;
    const int srow = lane >> 3;
    const int scol = (lane & 7) * 8;

    f32x4 acc[4][4];
    const f32x4 z4 = {0.f, 0.f, 0.f, 0.f};
    #pragma unroll
    for (int i = 0; i < 4; ++i)
        #pragma unroll
        for (int j = 0; j < 4; ++j) acc[i][j] = z4;

    #pragma unroll
    for (int i = 0; i < 4; ++i) {
        const int seg = wid * 4 + i;
        const int row = seg * 8 + srow;
        gload16(xb + (size_t)(m0 + row) * EE + scol, smem + seg * 1024);
        gload16(wz + (size_t)(n0 + row) * EE + scol, smem + 16384 + seg * 1024);
    }
    __syncthreads();

    for (int kt = 0; kt < 12; ++kt) {
        const int cur = kt & 1;
        bf16_t* lA = (bf16_t*)(smem + cur * 32768);
        bf16_t* lB = (bf16_t*)(smem + cur * 32768 + 16384);

        if (kt < 11) {
            const int k0 = (kt + 1) * 64;
            char* nb = smem + (cur ^ 1) * 32768;
            #pragma unroll
            for (int i = 0; i < 4; ++i) {
                const int seg = wid * 4 + i;
                const int row = seg * 8 + srow;
                gload16(xb + (size_t)(m0 + row) * EE + k0 + scol, nb + seg * 1024);
                gload16(wz + (size_t)(n0 + row) * EE + k0 + scol, nb + 16384 + seg * 1024);
            }
        }

        #pragma unroll
        for (int kk = 0; kk < 2; ++kk) {
            bf16x8 af[4], bfr[4];
            #pragma unroll
            for (int mi = 0; mi < 4; ++mi)
                af[mi] = *(const bf16x8*)(&lA[(wr * 64 + mi * 16 + lr) * 64 + kk * 32 + lg * 8]);
            #pragma unroll
            for (int ni = 0; ni < 4; ++ni)
                bfr[ni] = *(const bf16x8*)(&lB[(wc * 64 + ni * 16 + lr) * 64 + kk * 32 + lg * 8]);
            #pragma unroll
            for (int mi = 0; mi < 4; ++mi)
                #pragma unroll
                for (int ni = 0; ni < 4; ++ni)
                    acc[mi][ni] = mfma16(af[mi], bfr[ni], acc[mi][ni]);
        }
        __syncthreads();
    }

    #pragma unroll
    for (int mi = 0; mi < 4; ++mi)
        #pragma unroll
        for (int ni = 0; ni < 4; ++ni) {
            const int nl = wc * 64 + ni * 16 + lr;
            const float bn = bias[n0 + nl];
            #pragma unroll
            for (int r = 0; r < 4; ++r) {
                const int ml_ = wr * 64 + mi * 16 + lg * 4 + r;
                ct[ml_ * 128 + nl] = (bf16_t)((acc[mi][ni][r] + bn) * scale);
            }
        }
    __syncthreads();

    if (z != 2) {
        #pragma unroll
        for (int it = 0; it < 8; ++it) {
            const int idx = it * 2048 + tid * 8;
            const int row = idx >> 7, col = idx & 127;
            const int m = m0 + row, n = n0 + col;
            const int h = n >> 6, d = n & 63;
            const int bb = m >> 12, t = m & 4095;
            *(bf16x8*)(dst + (((size_t)bb * HH + h) * TT + t) * DH + d) = *(const bf16x8*)(&ct[idx]);
        }
    } else {
        const int bb = m0 >> 12, tbase = m0 & 4095;
        #pragma unroll
        for (int it = 0; it < 8; ++it) {
            const int idx = it * 2048 + tid * 8;
            const int nl = idx >> 7;
            const int tp0 = idx & 127;
            const int h = (n0 + nl) >> 6, d = (n0 + nl) & 63;
            bf16x8 v;
            #pragma unroll
            for (int j = 0; j < 8; ++j) {
                const int tpl = tp0 + j;
                const int tau = tpl >> 6, s = tpl & 63;
                const int tl = tau * 64 + (s & 3) * 16 + (s >> 2);
                v[j] = ct[tl * 128 + nl];
            }
            *(bf16x8*)(vTp + (((size_t)bb * HH + h) * DH + d) * TT + tbase + tp0) = v;
        }
    }
}

// ---------------- fused attention: blocks [0,384) GLOBAL attn; [384,1920) local ----
// gattn first so its latency-bound blocks co-reside with lattn round 1 (no tail).
// gattn v2: register-blocked QK (16 ds_reads/thread, was 1024), s_acc kept in
// regs through the exp pass, f32x4 sc reads + 8 accumulator chains in PV.
__global__ __launch_bounds__(256) void k_attn(const bf16_t* __restrict__ qs,
                                              const bf16_t* __restrict__ ks,
                                              const bf16_t* __restrict__ vT,
                                              const float* __restrict__ x,
                                              const float* __restrict__ Wqg,
                                              const float* __restrict__ bqg,
                                              const bf16_t* __restrict__ kgl,
                                              const bf16_t* __restrict__ vgl,
                                              float* __restrict__ out) {
    __shared__ __align__(16) char smem[26880];
    const int tid = threadIdx.x;

    if (blockIdx.x >= 384) {
        // =================== local windowed attention ===================
        const int gx0 = blockIdx.x - 384;              // 0..1535; 384%8==0 keeps swizzle
        const int gx = (gx0 & 7) * 192 + (gx0 >> 3);   // 3 consecutive bh per XCD
        const int q4 = gx & 3;
        const int c = (gx >> 2) & 15;
        const int bh = gx >> 6;          // 0..23
        const int b = bh / HH, h = bh % HH;
        const int w = tid >> 6;          // wave id 0..3
        const int parity = w & 1;
        const int qbase = (w >> 1) * 32;
        const int lane = tid & 63, lg = lane >> 4, lr = lane & 15;

        const bf16_t* qp = qs + ((size_t)bh * TT + c * WW + q4 * 64 + qbase) * DH;
        const bf16_t* kp = ks + (size_t)bh * TT * DH;
        const bf16_t* vp = vT + (size_t)bh * DH * TT;

        bf16_t* Pw  = (bf16_t*)(smem + (size_t)w * 4608);
        bf16_t* Kg  = (bf16_t*)(smem + 18432);
        bf16_t* VgT = (bf16_t*)(smem + 20736);
        float*  ml  = (float*)(smem + 25856);
        float*  OmP = (float*)(smem + (size_t)(w >> 1) * 8192);

        if (w == 0) {
            #pragma unroll
            for (int i = 0; i < 2; ++i) {
                int idx = i * 64 + lane;
                int r = idx >> 3, d8 = (idx & 7) * 8;
                *(bf16x8*)(&Kg[r * 72 + d8]) = *(const bf16x8*)(kp + (size_t)r * WW * DH + d8);
            }
        } else if (w == 1) {
            #pragma unroll
            for (int g = 0; g < 32; ++g)
                VgT[lane * 40 + g] = (g < 16) ? vp[(size_t)lane * TT + g * WW] : (bf16_t)0.f;
        }

        bf16x8 Qf[2][2];
        #pragma unroll
        for (int mi = 0; mi < 2; ++mi)
            #pragma unroll
            for (int kk = 0; kk < 2; ++kk)
                Qf[mi][kk] = *(const bf16x8*)(qp + (size_t)(mi * 16 + lr) * DH + kk * 32 + lg * 8);

        f32x4 O[2][4];
        const f32x4 z4 = {0.f, 0.f, 0.f, 0.f};
        #pragma unroll
        for (int i = 0; i < 2; ++i)
            #pragma unroll
            for (int j = 0; j < 4; ++j) O[i][j] = z4;

        float m_own[8], l_own[8];
        #pragma unroll
        for (int i = 0; i < 8; ++i) { m_own[i] = -1e30f; l_own[i] = 0.f; }

        __syncthreads();

        for (int ts = parity; ts < 10; ts += 2) {
            const bool isg = (ts == 0);
            const int jt = q4 + ts - 1;
            const int ttile = 4 * (c - 1) + jt;
            if (!isg && (ttile < 0 || ttile > 63)) continue;
            const bool gdrop = !isg && ((jt & 3) == 0);
            const bool anymask = (ts == 1) || (ts == 9) || gdrop;

            bf16x8 kf[4][2];
            if (isg) {
                #pragma unroll
                for (int kk = 0; kk < 2; ++kk)
                    kf[0][kk] = *(const bf16x8*)(&Kg[lr * 72 + kk * 32 + lg * 8]);
            } else {
                const bf16_t* ktp = kp + (size_t)ttile * 64 * DH;
                #pragma unroll
                for (int ni = 0; ni < 4; ++ni)
                    #pragma unroll
                    for (int kk = 0; kk < 2; ++kk)
                        kf[ni][kk] = *(const bf16x8*)(ktp + (size_t)(ni * 16 + lr) * DH + kk * 32 + lg * 8);
            }

            #pragma unroll
            for (int mi = 0; mi < 2; ++mi) {
                f32x4 S[4] = {z4, z4, z4, z4};
                if (isg) {
                    #pragma unroll
                    for (int kk = 0; kk < 2; ++kk)
                        S[0] = mfma16(Qf[mi][kk], kf[0][kk], S[0]);
                } else {
                    #pragma unroll
                    for (int kk = 0; kk < 2; ++kk)
                        #pragma unroll
                        for (int ni = 0; ni < 4; ++ni)
                            S[ni] = mfma16(Qf[mi][kk], kf[ni][kk], S[ni]);
                }

                #pragma unroll
                for (int r = 0; r < 4; ++r) {
                    const int lrow = mi * 16 + lg * 4 + r;
                    const int row = qbase + lrow;
                    const int idx = mi * 4 + r;
                    float sv[4];
                    if (anymask || isg) {
                        #pragma unroll
                        for (int ni = 0; ni < 4; ++ni) {
                            const int cc = ni * 16 + lr;
                            bool ok = isg ? (ni == 0)
                                          : !((ts == 1 && cc < row) || (ts == 9 && cc > row) ||
                                              (gdrop && cc == 0));
                            sv[ni] = ok ? S[ni][r] : -1e30f;
                        }
                    } else {
                        #pragma unroll
                        for (int ni = 0; ni < 4; ++ni) sv[ni] = S[ni][r];
                    }
                    const float town = fmaxf(fmaxf(sv[0], sv[1]), fmaxf(sv[2], sv[3]));
                    if (!__all(town <= m_own[idx] + 8.f)) {
                        float tmax = town;
                        tmax = fmaxf(tmax, __shfl_xor(tmax, 1));
                        tmax = fmaxf(tmax, __shfl_xor(tmax, 2));
                        tmax = fmaxf(tmax, __shfl_xor(tmax, 4));
                        tmax = fmaxf(tmax, __shfl_xor(tmax, 8));
                        const float m2 = fmaxf(m_own[idx], tmax);
                        const float scr = __expf(m_own[idx] - m2);
                        m_own[idx] = m2;
                        l_own[idx] *= scr;
                        #pragma unroll
                        for (int di = 0; di < 4; ++di) O[mi][di][r] *= scr;
                    }
                    const float p0 = __expf(sv[0] - m_own[idx]);
                    const float p1 = __expf(sv[1] - m_own[idx]);
                    const float p2 = __expf(sv[2] - m_own[idx]);
                    const float p3 = __expf(sv[3] - m_own[idx]);
                    l_own[idx] += (p0 + p1) + (p2 + p3);
                    if (isg) {
                        Pw[lrow * 72 + 0 * 16 + lr] = (bf16_t)p0;
                        Pw[lrow * 72 + 1 * 16 + lr] = (bf16_t)p1;
                        Pw[lrow * 72 + 2 * 16 + lr] = (bf16_t)p2;
                        Pw[lrow * 72 + 3 * 16 + lr] = (bf16_t)p3;
                    } else {
                        uint32_t d0, d1;
                        asm("v_cvt_pk_bf16_f32 %0, %1, %2" : "=v"(d0) : "v"(p0), "v"(p1));
                        asm("v_cvt_pk_bf16_f32 %0, %1, %2" : "=v"(d1) : "v"(p2), "v"(p3));
                        uint32_t* dstp = (uint32_t*)(&Pw[lrow * 72 + lr * 4]);
                        dstp[0] = d0;
                        dstp[1] = d1;
                    }
                }
            }

            asm volatile("s_waitcnt lgkmcnt(0)" ::: "memory");
            __builtin_amdgcn_sched_barrier(0);

            #pragma unroll
            for (int kkp = 0; kkp < 2; ++kkp) {
                if (isg && kkp == 1) continue;
                bf16x8 pa[2];
                #pragma unroll
                for (int mi = 0; mi < 2; ++mi)
                    pa[mi] = *(const bf16x8*)(&Pw[(mi * 16 + lr) * 72 + kkp * 32 + lg * 8]);
                #pragma unroll
                for (int di = 0; di < 4; ++di) {
                    bf16x8 vf;
                    if (isg)
                        vf = *(const bf16x8*)(&VgT[(di * 16 + lr) * 40 + lg * 8]);
                    else
                        vf = *(const bf16x8*)(vp + (size_t)(di * 16 + lr) * TT + ttile * 64 + kkp * 32 + lg * 8);
                    #pragma unroll
                    for (int mi = 0; mi < 2; ++mi) O[mi][di] = mfma16(pa[mi], vf, O[mi][di]);
                }
            }
        }

        #pragma unroll
        for (int i = 0; i < 8; ++i) {
            float l = l_own[i];
            l += __shfl_xor(l, 1);
            l += __shfl_xor(l, 2);
            l += __shfl_xor(l, 4);
            l += __shfl_xor(l, 8);
            l_own[i] = l;
        }

        #pragma unroll
        for (int mi = 0; mi < 2; ++mi)
            #pragma unroll
            for (int r = 0; r < 4; ++r)
                if (lr == 0) {
                    int lrow = mi * 16 + lg * 4 + r;
                    ml[w * 64 + lrow]      = m_own[mi * 4 + r];
                    ml[w * 64 + 32 + lrow] = l_own[mi * 4 + r];
                }
        __syncthreads();

        if (parity) {
            #pragma unroll
            for (int mi = 0; mi < 2; ++mi)
                #pragma unroll
                for (int r = 0; r < 4; ++r) {
                    const int lrow = mi * 16 + lg * 4 + r;
                    const int idx = mi * 4 + r;
                    const float mstar = fmaxf(ml[(w - 1) * 64 + lrow], m_own[idx]);
                    const float s1 = __expf(m_own[idx] - mstar);
                    #pragma unroll
                    for (int di = 0; di < 4; ++di)
                        OmP[lrow * 64 + di * 16 + lr] = O[mi][di][r] * s1;
                    if (lr == 0) ml[w * 64 + 32 + lrow] = l_own[idx] * s1;
                }
        }
        __syncthreads();

        if (!parity) {
            const bool gskip = (q4 == 0) && (qbase == 0);   // row 0 is a global token
            const size_t outbase = ((size_t)b * TT + c * WW + q4 * 64 + qbase) * EE + h * DH;
            #pragma unroll
            for (int mi = 0; mi < 2; ++mi)
                #pragma unroll
                for (int r = 0; r < 4; ++r) {
                    const int lrow = mi * 16 + lg * 4 + r;
                    const int idx = mi * 4 + r;
                    const float m1 = ml[(w + 1) * 64 + lrow];
                    const float mstar = fmaxf(m_own[idx], m1);
                    const float s0 = __expf(m_own[idx] - mstar);
                    const float l = l_own[idx] * s0 + ml[(w + 1) * 64 + 32 + lrow];
                    const float linv = 1.f / l;
                    if (gskip && lrow == 0) continue;   // gattn owns this row
                    #pragma unroll
                    for (int di = 0; di < 4; ++di)
                        out[outbase + (size_t)lrow * EE + di * 16 + lr] =
                            (O[mi][di][r] * s0 + OmP[lrow * 64 + di * 16 + lr]) * linv;
                }
        }
    } else {
        // =================== global-token attention (fused qg) ===================
        const int gx0 = blockIdx.x;              // 0..383
        const int xcd = gx0 & 7, y = gx0 >> 3;   // y 0..47
        const int bh = xcd * 3 + (y >> 4);       // 0..23
        const int g = y & 15;
        const int b = bh / HH, h = bh % HH;
        const int lane = tid & 63, w = tid >> 6;

        float* qrow = (float*)smem;              // [64]
        float* sc   = (float*)(smem + 256);      // [4096]
        float* red  = (float*)(smem + 16640);    // [256]
        float* xr   = (float*)(smem + 17664);    // [768]

        const float* xrow = x + ((size_t)b * TT + g * WW) * EE;
        for (int i = tid; i < EE; i += 256) xr[i] = xrow[i];
        __syncthreads();
        {
            const int d = tid & 63;
            const int e0 = (tid >> 6) * 192;
            float p = 0.f;
            for (int e = e0; e < e0 + 192; e += 4) {
                f32x4 xv = *(const f32x4*)&xr[e];
                p += xv[0] * Wqg[(size_t)e * EE + h * DH + d]
                   + xv[1] * Wqg[(size_t)(e + 1) * EE + h * DH + d]
                   + xv[2] * Wqg[(size_t)(e + 2) * EE + h * DH + d]
                   + xv[3] * Wqg[(size_t)(e + 3) * EE + h * DH + d];
            }
            red[tid] = p;
        }
        __syncthreads();
        if (tid < DH)
            qrow[tid] = (red[tid] + red[64 + tid] + red[128 + tid] + red[192 + tid]
                         + bqg[h * DH + tid]) * 0.125f;
        __syncthreads();

        // QK: register-blocked over d (16 LDS reads/thread total); s_acc in regs
        const bf16_t* kp = kgl + (size_t)bh * TT * DH;
        float s_acc[16];
        #pragma unroll
        for (int i = 0; i < 16; ++i) s_acc[i] = 0.f;
        #pragma unroll
        for (int d0 = 0; d0 < DH; d0 += 8) {
            const f32x4 qa = *(const f32x4*)&qrow[d0];
            const f32x4 qb = *(const f32x4*)&qrow[d0 + 4];
            #pragma unroll
            for (int i = 0; i < 16; ++i) {
                bf16x8 kv = *(const bf16x8*)(kp + (size_t)(tid + 256 * i) * DH + d0);
                s_acc[i] += qa[0] * (float)kv[0] + qa[1] * (float)kv[1]
                          + qa[2] * (float)kv[2] + qa[3] * (float)kv[3]
                          + qb[0] * (float)kv[4] + qb[1] * (float)kv[5]
                          + qb[2] * (float)kv[6] + qb[3] * (float)kv[7];
            }
        }
        float lmax = -1e30f;
        #pragma unroll
        for (int i = 0; i < 16; ++i) lmax = fmaxf(lmax, s_acc[i]);
        #pragma unroll
        for (int off = 32; off; off >>= 1) lmax = fmaxf(lmax, __shfl_xor(lmax, off));
        if (lane == 0) red[w] = lmax;
        __syncthreads();
        const float M = fmaxf(fmaxf(red[0], red[1]), fmaxf(red[2], red[3]));
        float lsum = 0.f;
        #pragma unroll
        for (int i = 0; i < 16; ++i) {
            float p = __expf(s_acc[i] - M);
            sc[tid + 256 * i] = p;
            lsum += p;
        }
        #pragma unroll
        for (int off = 32; off; off >>= 1) lsum += __shfl_xor(lsum, off);
        __syncthreads();                 // red[0..3] reads done; sc writes pending
        if (lane == 0) red[64 + w] = lsum;
        __syncthreads();
        const float SUM = red[64] + red[65] + red[66] + red[67];
        __syncthreads();                 // sc fully published before PV

        // PV: 8 independent chains, f32x4 sc reads
        const bf16_t* vp = vgl + (size_t)bh * TT * DH;
        float a[8];
        #pragma unroll
        for (int i = 0; i < 8; ++i) a[i] = 0.f;
        const int tbase = w * 1024;
        for (int t = tbase; t < tbase + 1024; t += 8) {
            const f32x4 s0 = *(const f32x4*)&sc[t];
            const f32x4 s1 = *(const f32x4*)&sc[t + 4];
            a[0] += s0[0] * (float)vp[(size_t)(t + 0) * DH + lane];
            a[1] += s0[1] * (float)vp[(size_t)(t + 1) * DH + lane];
            a[2] += s0[2] * (float)vp[(size_t)(t + 2) * DH + lane];
            a[3] += s0[3] * (float)vp[(size_t)(t + 3) * DH + lane];
            a[4] += s1[0] * (float)vp[(size_t)(t + 4) * DH + lane];
            a[5] += s1[1] * (float)vp[(size_t)(t + 5) * DH + lane];
            a[6] += s1[2] * (float)vp[(size_t)(t + 6) * DH + lane];
            a[7] += s1[3] * (float)vp[(size_t)(t + 7) * DH + lane];
        }
        red[tid] = ((a[0] + a[1]) + (a[2] + a[3])) + ((a[4] + a[5]) + (a[6] + a[7]));
        __syncthreads();
        if (w == 0) {
            float tot = red[lane] + red[64 + lane] + red[128 + lane] + red[192 + lane];
            out[((size_t)b * TT + g * WW) * EE + h * DH + lane] = tot / SUM;
        }
    }
}

// ---------------- launch ----------------
extern "C" void kernel_launch(void* const* d_in, const int* in_sizes, int n_in,
                              void* d_out, int out_size, void* d_ws, size_t ws_size,
                              hipStream_t stream) {
    const float* x   = (const float*)d_in[0];
    const float* Wq  = (const float*)d_in[1];
    const float* bq  = (const float*)d_in[2];
    const float* Wk  = (const float*)d_in[3];
    const float* bk  = (const float*)d_in[4];
    const float* Wv  = (const float*)d_in[5];
    const float* bv  = (const float*)d_in[6];
    const float* Wqg = (const float*)d_in[7];
    const float* bqg = (const float*)d_in[8];
    const float* Wkg = (const float*)d_in[9];
    const float* bkg = (const float*)d_in[10];
    const float* Wvg = (const float*)d_in[11];
    const float* bvg = (const float*)d_in[12];
    float* out = (float*)d_out;

    const size_t NX = (size_t)BB * TT * EE;          // 6,291,456
    const size_t NW = (size_t)EE * EE;               // 589,824
    const size_t NP = (size_t)BB * HH * TT * DH;     // 6,291,456

    bf16_t* xb   = (bf16_t*)d_ws;
    bf16_t* wt   = xb + NX;
    bf16_t* proj = wt + 5 * NW;
    bf16_t* vT   = proj + 5 * NP;

    (void)bvg; (void)in_sizes; (void)n_in; (void)out_size; (void)ws_size;

    k_prep<<<dim3(3792), 256, 0, stream>>>(x, xb, Wq, Wk, Wv, Wkg, Wvg, wt);
    k_gemm<<<dim3(64, 6, 5), 256, 0, stream>>>(xb, wt, bq, bk, bv, bkg, bvg, proj, vT);
    k_attn<<<dim3(1920), 256, 0, stream>>>(proj, proj + NP, vT, x, Wqg, bqg,
                                           proj + 3 * NP, proj + 4 * NP, out);
}

// Round 15
// 215.162 us; speedup vs baseline: 1.1065x; 1.1065x over previous
//
#include <hip/hip_runtime.h>
#include <stdint.h>
#include <stddef.h>

// Problem constants
#define BB 2
#define TT 4096
#define EE 768
#define HH 12
#define DH 64
#define WW 256
#define NCHUNK 16
#define GG 16

typedef __bf16 bf16_t;
typedef __bf16 bf16x8 __attribute__((ext_vector_type(8)));
typedef float f32x4 __attribute__((ext_vector_type(4)));

__device__ inline f32x4 mfma16(bf16x8 a, bf16x8 b, f32x4 c) {
    return __builtin_amdgcn_mfma_f32_16x16x32_bf16(a, b, c, 0, 0, 0);
}

__device__ inline void gload16(const void* g, void* l) {
    __builtin_amdgcn_global_load_lds(
        (const __attribute__((address_space(1))) void*)g,
        (__attribute__((address_space(3))) void*)l, 16, 0, 0);
}

// ---------------- fused prep: blocks [0,3072) x->xb bf16; [3072,3792) W->Wt ----------
__global__ __launch_bounds__(256) void k_prep(const float* __restrict__ x,
                                              bf16_t* __restrict__ xb,
                                              const float* __restrict__ w0,
                                              const float* __restrict__ w1,
                                              const float* __restrict__ w2,
                                              const float* __restrict__ w3,
                                              const float* __restrict__ w4,
                                              bf16_t* __restrict__ wt) {
    __shared__ __align__(16) bf16_t ls[64 * 65];
    const int tid = threadIdx.x;
    if (blockIdx.x < 3072) {
        const int i = (blockIdx.x * 256 + tid) * 8;
        f32x4 a = *(const f32x4*)(x + i);
        f32x4 b = *(const f32x4*)(x + i + 4);
        bf16x8 o;
        o[0] = (bf16_t)a[0]; o[1] = (bf16_t)a[1]; o[2] = (bf16_t)a[2]; o[3] = (bf16_t)a[3];
        o[4] = (bf16_t)b[0]; o[5] = (bf16_t)b[1]; o[6] = (bf16_t)b[2]; o[7] = (bf16_t)b[3];
        *(bf16x8*)(xb + i) = o;
    } else {
        const int idx0 = blockIdx.x - 3072;         // 0..719
        const int z = idx0 / 144;
        const int rr = idx0 % 144;
        const int k0 = (rr / 12) * 64;
        const int n0 = (rr % 12) * 64;
        const float* W = (z == 0) ? w0 : (z == 1) ? w1 : (z == 2) ? w2 : (z == 3) ? w3 : w4;
        #pragma unroll
        for (int i = 0; i < 16; ++i) {
            int idx = i * 256 + tid;
            int kr = idx >> 6, nc = idx & 63;
            ls[nc * 65 + kr] = (bf16_t)W[(size_t)(k0 + kr) * EE + n0 + nc];
        }
        __syncthreads();
        bf16_t* o = wt + (size_t)z * EE * EE;
        #pragma unroll
        for (int i = 0; i < 16; ++i) {
            int idx = i * 256 + tid;
            int nr = idx >> 6, kc = idx & 63;
            o[(size_t)(n0 + nr) * EE + k0 + kc] = ls[nr * 65 + kc];
        }
    }
}

// ---------------- projection GEMM (v12, unchanged): dbuf, 1 barrier/K-step --------
__global__ __launch_bounds__(256) void k_gemm(const bf16_t* __restrict__ xb,
                                              const bf16_t* __restrict__ wt,
                                              const float* __restrict__ b0,
                                              const float* __restrict__ b1,
                                              const float* __restrict__ b2,
                                              const float* __restrict__ b3,
                                              const float* __restrict__ b4,
                                              bf16_t* __restrict__ proj,
                                              bf16_t* __restrict__ vTp) {
    const int tid = threadIdx.x;
    const int z = blockIdx.z;
    const int m0 = blockIdx.x * 128;
    const int n0 = blockIdx.y * 128;
    const float* bias = (z == 0) ? b0 : (z == 1) ? b1 : (z == 2) ? b2 : (z == 3) ? b3 : b4;
    const float scale = (z == 0) ? 0.125f : 1.0f;
    const bf16_t* wz = wt + (size_t)z * EE * EE;
    bf16_t* dst = proj + (size_t)z * BB * HH * TT * DH;

    __shared__ __align__(16) char smem[65536];
    bf16_t* ct = (bf16_t*)smem;             // [128*128] overlay

    const int lane = tid & 63, wid = tid >> 6;
    const int wr = wid >> 1, wc = wid & 1;
    const int lg = lane >> 4, lr = lane & 15;
    const int srow = lane >> 3;
    const int scol = (lane & 7) * 8;

    f32x4 acc[4][4];
    const f32x4 z4 = {0.f, 0.f, 0.f, 0.f};
    #pragma unroll
    for (int i = 0; i < 4; ++i)
        #pragma unroll
        for (int j = 0; j < 4; ++j) acc[i][j] = z4;

    #pragma unroll
    for (int i = 0; i < 4; ++i) {
        const int seg = wid * 4 + i;
        const int row = seg * 8 + srow;
        gload16(xb + (size_t)(m0 + row) * EE + scol, smem + seg * 1024);
        gload16(wz + (size_t)(n0 + row) * EE + scol, smem + 16384 + seg * 1024);
    }
    __syncthreads();

    for (int kt = 0; kt < 12; ++kt) {
        const int cur = kt & 1;
        bf16_t* lA = (bf16_t*)(smem + cur * 32768);
        bf16_t* lB = (bf16_t*)(smem + cur * 32768 + 16384);

        if (kt < 11) {
            const int k0 = (kt + 1) * 64;
            char* nb = smem + (cur ^ 1) * 32768;
            #pragma unroll
            for (int i = 0; i < 4; ++i) {
                const int seg = wid * 4 + i;
                const int row = seg * 8 + srow;
                gload16(xb + (size_t)(m0 + row) * EE + k0 + scol, nb + seg * 1024);
                gload16(wz + (size_t)(n0 + row) * EE + k0 + scol, nb + 16384 + seg * 1024);
            }
        }

        #pragma unroll
        for (int kk = 0; kk < 2; ++kk) {
            bf16x8 af[4], bfr[4];
            #pragma unroll
            for (int mi = 0; mi < 4; ++mi)
                af[mi] = *(const bf16x8*)(&lA[(wr * 64 + mi * 16 + lr) * 64 + kk * 32 + lg * 8]);
            #pragma unroll
            for (int ni = 0; ni < 4; ++ni)
                bfr[ni] = *(const bf16x8*)(&lB[(wc * 64 + ni * 16 + lr) * 64 + kk * 32 + lg * 8]);
            #pragma unroll
            for (int mi = 0; mi < 4; ++mi)
                #pragma unroll
                for (int ni = 0; ni < 4; ++ni)
                    acc[mi][ni] = mfma16(af[mi], bfr[ni], acc[mi][ni]);
        }
        __syncthreads();
    }

    #pragma unroll
    for (int mi = 0; mi < 4; ++mi)
        #pragma unroll
        for (int ni = 0; ni < 4; ++ni) {
            const int nl = wc * 64 + ni * 16 + lr;
            const float bn = bias[n0 + nl];
            #pragma unroll
            for (int r = 0; r < 4; ++r) {
                const int ml_ = wr * 64 + mi * 16 + lg * 4 + r;
                ct[ml_ * 128 + nl] = (bf16_t)((acc[mi][ni][r] + bn) * scale);
            }
        }
    __syncthreads();

    if (z != 2) {
        #pragma unroll
        for (int it = 0; it < 8; ++it) {
            const int idx = it * 2048 + tid * 8;
            const int row = idx >> 7, col = idx & 127;
            const int m = m0 + row, n = n0 + col;
            const int h = n >> 6, d = n & 63;
            const int bb = m >> 12, t = m & 4095;
            *(bf16x8*)(dst + (((size_t)bb * HH + h) * TT + t) * DH + d) = *(const bf16x8*)(&ct[idx]);
        }
    } else {
        const int bb = m0 >> 12, tbase = m0 & 4095;
        #pragma unroll
        for (int it = 0; it < 8; ++it) {
            const int idx = it * 2048 + tid * 8;
            const int nl = idx >> 7;
            const int tp0 = idx & 127;
            const int h = (n0 + nl) >> 6, d = (n0 + nl) & 63;
            bf16x8 v;
            #pragma unroll
            for (int j = 0; j < 8; ++j) {
                const int tpl = tp0 + j;
                const int tau = tpl >> 6, s = tpl & 63;
                const int tl = tau * 64 + (s & 3) * 16 + (s >> 2);
                v[j] = ct[tl * 128 + nl];
            }
            *(bf16x8*)(vTp + (((size_t)bb * HH + h) * DH + d) * TT + tbase + tp0) = v;
        }
    }
}

// ---------------- fused attention: blocks [0,1536) local attn; [1536,1920) global ----
// r13 structure restored (gattn LAST). Only change vs r13: gattn PV is 8-row
// vectorized (128x bf16x8 coalesced loads/thread instead of 1024x 2B scalars).
__global__ __launch_bounds__(256) void k_attn(const bf16_t* __restrict__ qs,
                                              const bf16_t* __restrict__ ks,
                                              const bf16_t* __restrict__ vT,
                                              const float* __restrict__ x,
                                              const float* __restrict__ Wqg,
                                              const float* __restrict__ bqg,
                                              const bf16_t* __restrict__ kgl,
                                              const bf16_t* __restrict__ vgl,
                                              float* __restrict__ out) {
    __shared__ __align__(16) char smem[26880];
    const int tid = threadIdx.x;

    if (blockIdx.x < 1536) {
        // =================== local windowed attention (r11/r13, unchanged) ==========
        const int gx0 = blockIdx.x;
        const int gx = (gx0 & 7) * 192 + (gx0 >> 3);   // 3 consecutive bh per XCD
        const int q4 = gx & 3;
        const int c = (gx >> 2) & 15;
        const int bh = gx >> 6;          // 0..23
        const int b = bh / HH, h = bh % HH;
        const int w = tid >> 6;          // wave id 0..3
        const int parity = w & 1;
        const int qbase = (w >> 1) * 32;
        const int lane = tid & 63, lg = lane >> 4, lr = lane & 15;

        const bf16_t* qp = qs + ((size_t)bh * TT + c * WW + q4 * 64 + qbase) * DH;
        const bf16_t* kp = ks + (size_t)bh * TT * DH;
        const bf16_t* vp = vT + (size_t)bh * DH * TT;

        bf16_t* Pw  = (bf16_t*)(smem + (size_t)w * 4608);
        bf16_t* Kg  = (bf16_t*)(smem + 18432);
        bf16_t* VgT = (bf16_t*)(smem + 20736);
        float*  ml  = (float*)(smem + 25856);
        float*  OmP = (float*)(smem + (size_t)(w >> 1) * 8192);

        if (w == 0) {
            #pragma unroll
            for (int i = 0; i < 2; ++i) {
                int idx = i * 64 + lane;
                int r = idx >> 3, d8 = (idx & 7) * 8;
                *(bf16x8*)(&Kg[r * 72 + d8]) = *(const bf16x8*)(kp + (size_t)r * WW * DH + d8);
            }
        } else if (w == 1) {
            #pragma unroll
            for (int g = 0; g < 32; ++g)
                VgT[lane * 40 + g] = (g < 16) ? vp[(size_t)lane * TT + g * WW] : (bf16_t)0.f;
        }

        bf16x8 Qf[2][2];
        #pragma unroll
        for (int mi = 0; mi < 2; ++mi)
            #pragma unroll
            for (int kk = 0; kk < 2; ++kk)
                Qf[mi][kk] = *(const bf16x8*)(qp + (size_t)(mi * 16 + lr) * DH + kk * 32 + lg * 8);

        f32x4 O[2][4];
        const f32x4 z4 = {0.f, 0.f, 0.f, 0.f};
        #pragma unroll
        for (int i = 0; i < 2; ++i)
            #pragma unroll
            for (int j = 0; j < 4; ++j) O[i][j] = z4;

        float m_own[8], l_own[8];
        #pragma unroll
        for (int i = 0; i < 8; ++i) { m_own[i] = -1e30f; l_own[i] = 0.f; }

        __syncthreads();

        for (int ts = parity; ts < 10; ts += 2) {
            const bool isg = (ts == 0);
            const int jt = q4 + ts - 1;
            const int ttile = 4 * (c - 1) + jt;
            if (!isg && (ttile < 0 || ttile > 63)) continue;
            const bool gdrop = !isg && ((jt & 3) == 0);
            const bool anymask = (ts == 1) || (ts == 9) || gdrop;

            bf16x8 kf[4][2];
            if (isg) {
                #pragma unroll
                for (int kk = 0; kk < 2; ++kk)
                    kf[0][kk] = *(const bf16x8*)(&Kg[lr * 72 + kk * 32 + lg * 8]);
            } else {
                const bf16_t* ktp = kp + (size_t)ttile * 64 * DH;
                #pragma unroll
                for (int ni = 0; ni < 4; ++ni)
                    #pragma unroll
                    for (int kk = 0; kk < 2; ++kk)
                        kf[ni][kk] = *(const bf16x8*)(ktp + (size_t)(ni * 16 + lr) * DH + kk * 32 + lg * 8);
            }

            #pragma unroll
            for (int mi = 0; mi < 2; ++mi) {
                f32x4 S[4] = {z4, z4, z4, z4};
                if (isg) {
                    #pragma unroll
                    for (int kk = 0; kk < 2; ++kk)
                        S[0] = mfma16(Qf[mi][kk], kf[0][kk], S[0]);
                } else {
                    #pragma unroll
                    for (int kk = 0; kk < 2; ++kk)
                        #pragma unroll
                        for (int ni = 0; ni < 4; ++ni)
                            S[ni] = mfma16(Qf[mi][kk], kf[ni][kk], S[ni]);
                }

                #pragma unroll
                for (int r = 0; r < 4; ++r) {
                    const int lrow = mi * 16 + lg * 4 + r;
                    const int row = qbase + lrow;
                    const int idx = mi * 4 + r;
                    float sv[4];
                    if (anymask || isg) {
                        #pragma unroll
                        for (int ni = 0; ni < 4; ++ni) {
                            const int cc = ni * 16 + lr;
                            bool ok = isg ? (ni == 0)
                                          : !((ts == 1 && cc < row) || (ts == 9 && cc > row) ||
                                              (gdrop && cc == 0));
                            sv[ni] = ok ? S[ni][r] : -1e30f;
                        }
                    } else {
                        #pragma unroll
                        for (int ni = 0; ni < 4; ++ni) sv[ni] = S[ni][r];
                    }
                    const float town = fmaxf(fmaxf(sv[0], sv[1]), fmaxf(sv[2], sv[3]));
                    if (!__all(town <= m_own[idx] + 8.f)) {
                        float tmax = town;
                        tmax = fmaxf(tmax, __shfl_xor(tmax, 1));
                        tmax = fmaxf(tmax, __shfl_xor(tmax, 2));
                        tmax = fmaxf(tmax, __shfl_xor(tmax, 4));
                        tmax = fmaxf(tmax, __shfl_xor(tmax, 8));
                        const float m2 = fmaxf(m_own[idx], tmax);
                        const float scr = __expf(m_own[idx] - m2);
                        m_own[idx] = m2;
                        l_own[idx] *= scr;
                        #pragma unroll
                        for (int di = 0; di < 4; ++di) O[mi][di][r] *= scr;
                    }
                    const float p0 = __expf(sv[0] - m_own[idx]);
                    const float p1 = __expf(sv[1] - m_own[idx]);
                    const float p2 = __expf(sv[2] - m_own[idx]);
                    const float p3 = __expf(sv[3] - m_own[idx]);
                    l_own[idx] += (p0 + p1) + (p2 + p3);
                    if (isg) {
                        Pw[lrow * 72 + 0 * 16 + lr] = (bf16_t)p0;
                        Pw[lrow * 72 + 1 * 16 + lr] = (bf16_t)p1;
                        Pw[lrow * 72 + 2 * 16 + lr] = (bf16_t)p2;
                        Pw[lrow * 72 + 3 * 16 + lr] = (bf16_t)p3;
                    } else {
                        uint32_t d0, d1;
                        asm("v_cvt_pk_bf16_f32 %0, %1, %2" : "=v"(d0) : "v"(p0), "v"(p1));
                        asm("v_cvt_pk_bf16_f32 %0, %1, %2" : "=v"(d1) : "v"(p2), "v"(p3));
                        uint32_t* dstp = (uint32_t*)(&Pw[lrow * 72 + lr * 4]);
                        dstp[0] = d0;
                        dstp[1] = d1;
                    }
                }
            }

            asm volatile("s_waitcnt lgkmcnt(0)" ::: "memory");
            __builtin_amdgcn_sched_barrier(0);

            #pragma unroll
            for (int kkp = 0; kkp < 2; ++kkp) {
                if (isg && kkp == 1) continue;
                bf16x8 pa[2];
                #pragma unroll
                for (int mi = 0; mi < 2; ++mi)
                    pa[mi] = *(const bf16x8*)(&Pw[(mi * 16 + lr) * 72 + kkp * 32 + lg * 8]);
                #pragma unroll
                for (int di = 0; di < 4; ++di) {
                    bf16x8 vf;
                    if (isg)
                        vf = *(const bf16x8*)(&VgT[(di * 16 + lr) * 40 + lg * 8]);
                    else
                        vf = *(const bf16x8*)(vp + (size_t)(di * 16 + lr) * TT + ttile * 64 + kkp * 32 + lg * 8);
                    #pragma unroll
                    for (int mi = 0; mi < 2; ++mi) O[mi][di] = mfma16(pa[mi], vf, O[mi][di]);
                }
            }
        }

        #pragma unroll
        for (int i = 0; i < 8; ++i) {
            float l = l_own[i];
            l += __shfl_xor(l, 1);
            l += __shfl_xor(l, 2);
            l += __shfl_xor(l, 4);
            l += __shfl_xor(l, 8);
            l_own[i] = l;
        }

        #pragma unroll
        for (int mi = 0; mi < 2; ++mi)
            #pragma unroll
            for (int r = 0; r < 4; ++r)
                if (lr == 0) {
                    int lrow = mi * 16 + lg * 4 + r;
                    ml[w * 64 + lrow]      = m_own[mi * 4 + r];
                    ml[w * 64 + 32 + lrow] = l_own[mi * 4 + r];
                }
        __syncthreads();

        if (parity) {
            #pragma unroll
            for (int mi = 0; mi < 2; ++mi)
                #pragma unroll
                for (int r = 0; r < 4; ++r) {
                    const int lrow = mi * 16 + lg * 4 + r;
                    const int idx = mi * 4 + r;
                    const float mstar = fmaxf(ml[(w - 1) * 64 + lrow], m_own[idx]);
                    const float s1 = __expf(m_own[idx] - mstar);
                    #pragma unroll
                    for (int di = 0; di < 4; ++di)
                        OmP[lrow * 64 + di * 16 + lr] = O[mi][di][r] * s1;
                    if (lr == 0) ml[w * 64 + 32 + lrow] = l_own[idx] * s1;
                }
        }
        __syncthreads();

        if (!parity) {
            const bool gskip = (q4 == 0) && (qbase == 0);   // row 0 is a global token
            const size_t outbase = ((size_t)b * TT + c * WW + q4 * 64 + qbase) * EE + h * DH;
            #pragma unroll
            for (int mi = 0; mi < 2; ++mi)
                #pragma unroll
                for (int r = 0; r < 4; ++r) {
                    const int lrow = mi * 16 + lg * 4 + r;
                    const int idx = mi * 4 + r;
                    const float m1 = ml[(w + 1) * 64 + lrow];
                    const float mstar = fmaxf(m_own[idx], m1);
                    const float s0 = __expf(m_own[idx] - mstar);
                    const float l = l_own[idx] * s0 + ml[(w + 1) * 64 + 32 + lrow];
                    const float linv = 1.f / l;
                    if (gskip && lrow == 0) continue;   // gattn owns this row
                    #pragma unroll
                    for (int di = 0; di < 4; ++di)
                        out[outbase + (size_t)lrow * EE + di * 16 + lr] =
                            (O[mi][di][r] * s0 + OmP[lrow * 64 + di * 16 + lr]) * linv;
                }
        }
    } else {
        // =================== global-token attention (fused qg; PV vectorized) =======
        const int gx0 = blockIdx.x - 1536;       // 1536%8==0 -> XCD mapping preserved
        const int xcd = gx0 & 7, y = gx0 >> 3;   // y 0..47
        const int bh = xcd * 3 + (y >> 4);       // 0..23
        const int g = y & 15;
        const int b = bh / HH, h = bh % HH;
        const int lane = tid & 63, w = tid >> 6;

        float* qrow = (float*)smem;              // [64]
        float* sc   = (float*)(smem + 256);      // [4096]
        float* red  = (float*)(smem + 16640);    // [256]
        float* xr   = (float*)(smem + 17664);    // [768]

        const float* xrow = x + ((size_t)b * TT + g * WW) * EE;
        for (int i = tid; i < EE; i += 256) xr[i] = xrow[i];
        __syncthreads();
        {
            const int d = tid & 63;
            const int e0 = (tid >> 6) * 192;
            float p = 0.f;
            for (int e = e0; e < e0 + 192; ++e)
                p += xr[e] * Wqg[(size_t)e * EE + h * DH + d];
            red[tid] = p;
        }
        __syncthreads();
        if (tid < DH)
            qrow[tid] = (red[tid] + red[64 + tid] + red[128 + tid] + red[192 + tid]
                         + bqg[h * DH + tid]) * 0.125f;
        __syncthreads();

        const bf16_t* kp = kgl + (size_t)bh * TT * DH;
        float lmax = -1e30f;
        for (int t = tid; t < TT; t += 256) {
            const bf16_t* kr = kp + (size_t)t * DH;
            float s = 0.f;
            #pragma unroll
            for (int d0 = 0; d0 < DH; d0 += 8) {
                bf16x8 kv = *(const bf16x8*)(kr + d0);
                #pragma unroll
                for (int jj = 0; jj < 8; ++jj) s += qrow[d0 + jj] * (float)kv[jj];
            }
            sc[t] = s;
            lmax = fmaxf(lmax, s);
        }
        #pragma unroll
        for (int off = 32; off; off >>= 1) lmax = fmaxf(lmax, __shfl_xor(lmax, off));
        if (lane == 0) red[w] = lmax;
        __syncthreads();
        const float M = fmaxf(fmaxf(red[0], red[1]), fmaxf(red[2], red[3]));
        float lsum = 0.f;
        for (int t = tid; t < TT; t += 256) {
            float p = __expf(sc[t] - M);
            sc[t] = p;
            lsum += p;
        }
        #pragma unroll
        for (int off = 32; off; off >>= 1) lsum += __shfl_xor(lsum, off);
        __syncthreads();
        if (lane == 0) red[64 + w] = lsum;
        __syncthreads();
        const float SUM = red[64] + red[65] + red[66] + red[67];
        __syncthreads();     // sc published + red[64..67] consumed before reuse

        // PV (vectorized): lane owns d-chunk dq..dq+7 and rows == rq (mod 8).
        // Per instruction: 8 consecutive rows x 128B = 1KB fully coalesced.
        const bf16_t* vp = vgl + (size_t)bh * TT * DH;
        const int rq = lane >> 3, dq = (lane & 7) * 8;
        float a[8];
        #pragma unroll
        for (int j = 0; j < 8; ++j) a[j] = 0.f;
        const int tbase = w * 1024;
        #pragma unroll 4
        for (int i = 0; i < 128; ++i) {
            const int t = tbase + rq + 8 * i;
            const float s = sc[t];                         // broadcast (8 lanes/addr)
            bf16x8 vv = *(const bf16x8*)(vp + (size_t)t * DH + dq);
            #pragma unroll
            for (int j = 0; j < 8; ++j) a[j] += s * (float)vv[j];
        }
        #pragma unroll
        for (int j = 0; j < 8; ++j) {
            float v = a[j];
            v += __shfl_xor(v, 8);
            v += __shfl_xor(v, 16);
            v += __shfl_xor(v, 32);
            a[j] = v;
        }
        if (rq == 0) {
            #pragma unroll
            for (int j = 0; j < 8; ++j) red[w * 64 + dq + j] = a[j];
        }
        __syncthreads();
        if (w == 0) {
            float tot = red[lane] + red[64 + lane] + red[128 + lane] + red[192 + lane];
            out[((size_t)b * TT + g * WW) * EE + h * DH + lane] = tot / SUM;
        }
    }
}

// ---------------- launch ----------------
extern "C" void kernel_launch(void* const* d_in, const int* in_sizes, int n_in,
                              void* d_out, int out_size, void* d_ws, size_t ws_size,
                              hipStream_t stream) {
    const float* x   = (const float*)d_in[0];
    const float* Wq  = (const float*)d_in[1];
    const float* bq  = (const float*)d_in[2];
    const float* Wk  = (const float*)d_in[3];
    const float* bk  = (const float*)d_in[4];
    const float* Wv  = (const float*)d_in[5];
    const float* bv  = (const float*)d_in[6];
    const float* Wqg = (const float*)d_in[7];
    const float* bqg = (const float*)d_in[8];
    const float* Wkg = (const float*)d_in[9];
    const float* bkg = (const float*)d_in[10];
    const float* Wvg = (const float*)d_in[11];
    const float* bvg = (const float*)d_in[12];
    float* out = (float*)d_out;

    const size_t NX = (size_t)BB * TT * EE;          // 6,291,456
    const size_t NW = (size_t)EE * EE;               // 589,824
    const size_t NP = (size_t)BB * HH * TT * DH;     // 6,291,456

    bf16_t* xb   = (bf16_t*)d_ws;
    bf16_t* wt   = xb + NX;
    bf16_t* proj = wt + 5 * NW;
    bf16_t* vT   = proj + 5 * NP;

    (void)bvg; (void)in_sizes; (void)n_in; (void)out_size; (void)ws_size;

    k_prep<<<dim3(3792), 256, 0, stream>>>(x, xb, Wq, Wk, Wv, Wkg, Wvg, wt);
    k_gemm<<<dim3(64, 6, 5), 256, 0, stream>>>(xb, wt, bq, bk, bv, bkg, bvg, proj, vT);
    k_attn<<<dim3(1920), 256, 0, stream>>>(proj, proj + NP, vT, x, Wqg, bqg,
                                           proj + 3 * NP, proj + 4 * NP, out);
}